// Round 6
// baseline (293.976 us; speedup 1.0000x reference)
//
#include <hip/hip_runtime.h>
#include <math.h>

// Problem constants (B=8, T=1024, C=32, F=256, D=128, K=512)
#define N_POS 8192
#define D_DIM 128
#define K_DIM 512
#define C_DIM 32
#define F_DIM 256

#define PT 64            // positions per NN tile
#define KW 128           // codewords per NN tile
#define NN_BLOCKS 512    // 128 ptiles x 4 ktiles
#define XG_BLOCKS 32     // 256 bt-rows each
#define GRID (NN_BLOCKS + XG_BLOCKS)

// zeroed-ws layout (floats): [0..7] accum (0=sse_rec,1=dsum,2=sse_mem),
// [8..135] ptile counters, [136] gcnt, [137..143] pad,
// [144..8335] g_rec, [8336..8591] S.  pd64 (u64[4*8192]) follows, un-zeroed.
#define ZWS_FLOATS 8592

// ---------------------------------------------------------------- reductions
__device__ __forceinline__ float block_reduce_256(float v) {
    __shared__ float sbuf[4];
    __syncthreads();
#pragma unroll
    for (int off = 32; off > 0; off >>= 1) v += __shfl_down(v, off);
    const int lane = threadIdx.x & 63;
    const int w    = threadIdx.x >> 6;
    if (lane == 0) sbuf[w] = v;
    __syncthreads();
    return (threadIdx.x == 0) ? (sbuf[0] + sbuf[1] + sbuf[2] + sbuf[3]) : 0.f;
}

__global__ __launch_bounds__(256, 2)
void fused_all(const float* __restrict__ H, const float* __restrict__ M,
               const float* __restrict__ Hdec, const float* __restrict__ W,
               const float* __restrict__ X, const float* __restrict__ w_d,
               float* __restrict__ zws,
               unsigned long long* __restrict__ pd64,
               float* __restrict__ out) {
    // NN half needs 32768 B (hT 8K + mT 16K + red64 8K); XG needs 49664 B.
    __shared__ __align__(16) char smem[49664];
    float* accum = zws;
    unsigned int* ptile_cnt = (unsigned int*)(zws + 8);
    unsigned int* gcnt      = (unsigned int*)(zws + 136);
    float* g_rec = zws + 144;
    float* S     = zws + 8336;
    const int tid = threadIdx.x;

    if (blockIdx.x < NN_BLOCKS) {
        // =================== NN: 64 pos x 128 k tile, 4x8 acc ===================
        float* hT = (float*)smem;                                  // [32][64]
        float* mT = hT + 2048;                                     // [32][128]
        unsigned long long* red64 = (unsigned long long*)(smem + 24576); // [16][64]

        const int ptile = blockIdx.x >> 2;       // 0..127
        const int ktile = blockIdx.x & 3;        // 0..3
        const int pos0  = ptile * PT;            // 64-aligned, never crosses b
        const int b     = pos0 >> 10;
        const int t0    = pos0 & 1023;
        const int k0    = ktile * KW;
        const float* Hb = H + (b << 17) + t0;

        const int p4 = (tid & 15) << 2;          // pos quad 0..60
        const int q8 = (tid >> 4) << 3;          // k octet 0..120

        float acc[4][8];
#pragma unroll
        for (int i = 0; i < 4; ++i)
#pragma unroll
            for (int j = 0; j < 8; ++j) acc[i][j] = 0.f;

        for (int ch = 0; ch < 4; ++ch) {         // 32-d chunks
            const int d0 = ch << 5;
            __syncthreads();
            {
                int idx = tid * 4;               // hT: 2048 floats
#pragma unroll
                for (int it = 0; it < 2; ++it, idx += 1024) {
                    const int d = idx >> 6, cc = idx & 63;
                    *(float4*)(hT + idx) =
                        *(const float4*)(Hb + ((size_t)(d0 + d) << 10) + cc);
                }
                idx = tid * 4;                   // mT: 4096 floats
#pragma unroll
                for (int it = 0; it < 4; ++it, idx += 1024) {
                    const int d = idx >> 7, cc = idx & 127;
                    *(float4*)(mT + idx) =
                        *(const float4*)(M + (size_t)(d0 + d) * K_DIM + k0 + cc);
                }
            }
            __syncthreads();
#pragma unroll 2
            for (int d = 0; d < 32; ++d) {
                const float4 h4 = *(const float4*)(hT + (d << 6) + p4);
                const float4 m0 = *(const float4*)(mT + (d << 7) + q8);
                const float4 m1 = *(const float4*)(mT + (d << 7) + q8 + 4);
                const float hh[4] = {h4.x, h4.y, h4.z, h4.w};
                const float mm[8] = {m0.x, m0.y, m0.z, m0.w, m1.x, m1.y, m1.z, m1.w};
#pragma unroll
                for (int i = 0; i < 4; ++i)
#pragma unroll
                    for (int j = 0; j < 8; ++j)
                        acc[i][j] += fabsf(hh[i] - mm[j]);
            }
        }

        // per-thread argmin over 8 ks (j ascending, strict < -> lowest k on tie),
        // packed u64 (dist_bits, k): u64-min == lexicographic (dist, k)
#pragma unroll
        for (int i = 0; i < 4; ++i) {
            float bd = acc[i][0];
            int   bj = 0;
#pragma unroll
            for (int j = 1; j < 8; ++j)
                if (acc[i][j] < bd) { bd = acc[i][j]; bj = j; }
            const unsigned int bk = (unsigned int)(k0 + q8 + bj);
            red64[(tid >> 4) * PT + p4 + i] =
                ((unsigned long long)__float_as_uint(bd) << 32) | bk;
        }
        __syncthreads();
        if (tid < PT) {
            unsigned long long best = red64[tid];
#pragma unroll
            for (int g = 1; g < 16; ++g) {
                const unsigned long long w = red64[g * PT + tid];
                if (w < best) best = w;
            }
            pd64[ktile * N_POS + pos0 + tid] = best;
        }
        __threadfence();     // release our pd64 slice device-wide
        __syncthreads();
        __shared__ int lastp;
        if (tid == 0) lastp = (atomicAdd(&ptile_cnt[ptile], 1u) == 3u);
        __syncthreads();
        if (lastp) {
            // merge 4 ktile winners (agent-scope atomic loads) + memory-loss SSE
            int* bi_l = (int*)smem;              // hT region is dead
            if (tid < PT) {
                unsigned long long best = ~0ull;
#pragma unroll
                for (int p = 0; p < 4; ++p) {
                    const unsigned long long w = __hip_atomic_load(
                        pd64 + p * N_POS + pos0 + tid,
                        __ATOMIC_RELAXED, __HIP_MEMORY_SCOPE_AGENT);
                    if (w < best) best = w;
                }
                bi_l[tid] = (int)(unsigned int)(best & 0xffffffffu);
            }
            __syncthreads();
            const int pl = tid & 63;
            const int dh = tid >> 6;             // 0..3, 32 d each
            const int bi = bi_l[pl];
            const float* Hp = H + (b << 17) + t0 + pl;
            float s = 0.f;
#pragma unroll 8
            for (int d = dh * 32; d < dh * 32 + 32; ++d) {
                const float e = Hp[(size_t)d << 10] - M[(size_t)d * K_DIM + bi];
                s += e * e;
            }
            const float r = block_reduce_256(s);
            if (tid == 0) atomicAdd(accum + 2, r);
        }
    } else {
        // ============ XG: xhat + E + loss_rec/disc + grec partials ============
        float* Wl = (float*)smem;                // [32][260]
        float* El = Wl + C_DIM * 260;            // [128][32]
        const int xb  = blockIdx.x - NN_BLOCKS;  // 0..31
        const int bt0 = xb << 8;                 // 256 rows per block

#pragma unroll
        for (int it = 0; it < 8; ++it) {         // stage W
            const int i = it * 1024 + tid * 4;
            const float4 v = *(const float4*)(W + i);
            *(float4*)(Wl + (i >> 8) * 260 + (i & 255)) = v;
        }
        const int c  = tid & 31;
        const int rg = tid >> 5;                 // 0..7
        const float wd = w_d[c];
        float gacc[C_DIM];
#pragma unroll
        for (int cc = 0; cc < C_DIM; ++cc) gacc[cc] = 0.f;
        float sf = 0.f, sse = 0.f, dp = 0.f;

        for (int pass = 0; pass < 2; ++pass) {
            const int rb = bt0 + pass * 128;
            __syncthreads();                     // Wl ready / El consumed
            float a[16];
#pragma unroll
            for (int j = 0; j < 16; ++j) a[j] = 0.f;
#pragma unroll 2
            for (int f0 = 0; f0 < F_DIM; f0 += 4) {
                const float4 w4 = *(const float4*)(Wl + c * 260 + f0);
#pragma unroll
                for (int j = 0; j < 16; ++j) {
                    const float4 h4 = *(const float4*)(
                        Hdec + (size_t)(rb + rg + 8 * j) * F_DIM + f0);
                    a[j] += h4.x * w4.x + h4.y * w4.y + h4.z * w4.z + h4.w * w4.w;
                }
            }
#pragma unroll
            for (int j = 0; j < 16; ++j) {
                const int r = rb + rg + 8 * j;
                const float e = a[j] - X[(size_t)r * C_DIM + c];
                El[(rg + 8 * j) * C_DIM + c] = e;
                sse += e * e;
                dp  += a[j] * wd;
            }
            __syncthreads();                     // El ready
            // grec: thread = f, E rows broadcast from LDS
#pragma unroll 1
            for (int i = 0; i < 128; ++i) {
                const float hd = Hdec[(size_t)(rb + i) * F_DIM + tid];
                sf += hd;
#pragma unroll
                for (int c4 = 0; c4 < 8; ++c4) {
                    const float4 e4 = *(const float4*)(El + i * C_DIM + c4 * 4);
                    gacc[c4 * 4 + 0] += e4.x * hd;
                    gacc[c4 * 4 + 1] += e4.y * hd;
                    gacc[c4 * 4 + 2] += e4.z * hd;
                    gacc[c4 * 4 + 3] += e4.w * hd;
                }
            }
        }
#pragma unroll 1
        for (int cc = 0; cc < C_DIM; ++cc)
            atomicAdd(&g_rec[cc * F_DIM + tid], gacc[cc]);
        atomicAdd(&S[tid], sf);
        const float rA = block_reduce_256(sse);
        if (tid == 0) atomicAdd(accum + 0, rA);
        const float rB = block_reduce_256(dp);
        if (tid == 0) atomicAdd(accum + 1, rB);
    }

    // ============== common epilogue: last block assembles the scalar ==========
    __shared__ int lastg;
    __threadfence();
    __syncthreads();
    if (tid == 0) lastg = (atomicAdd(gcnt, 1u) == (unsigned)(GRID - 1));
    __syncthreads();
    if (lastg) {
        float g2 = 0.f;
        for (int i = tid; i < 8192; i += 256) {
            const float v = __hip_atomic_load(g_rec + i, __ATOMIC_RELAXED,
                                              __HIP_MEMORY_SCOPE_AGENT);
            g2 += v * v;
        }
        const float rg2 = block_reduce_256(g2);
        const float vS = __hip_atomic_load(S + tid, __ATOMIC_RELAXED,
                                           __HIP_MEMORY_SCOPE_AGENT);
        const float rs2 = block_reduce_256(vS * vS);
        float wd2 = (tid < C_DIM) ? w_d[tid] * w_d[tid] : 0.f;
        if (tid < 64) {
#pragma unroll
            for (int off = 32; off > 0; off >>= 1) wd2 += __shfl_down(wd2, off);
        }
        if (tid == 0) {
            const float sse_rec = atomicAdd(accum + 0, 0.f);
            const float dsum    = atomicAdd(accum + 1, 0.f);
            const float sse_mem = atomicAdd(accum + 2, 0.f);
            const float loss_rec = sse_rec / 262144.f;         // /(B*T*C)
            const float loss_d   = -dsum / 8192.f;             // -mean over B*T
            const float loss_m   = 2.f * sse_mem / 1048576.f;  // 2*SSE/(B*D*T)
            const float ngrec    = (2.f / 262144.f) * sqrtf(rg2);
            const float ngd      = sqrtf(wd2 * rs2) / 8192.f;
            const float lmbda    = ngrec / (ngd + 1e-6f);
            out[0] = loss_rec + loss_m + lmbda * loss_d;       // ALPHA = 1
        }
    }
}

// ---------------------------------------------------------------- launcher
extern "C" void kernel_launch(void* const* d_in, const int* in_sizes, int n_in,
                              void* d_out, int out_size, void* d_ws, size_t ws_size,
                              hipStream_t stream) {
    const float* X    = (const float*)d_in[0];   // [8,1024,32]
    const float* H    = (const float*)d_in[1];   // [8,128,1024]
    const float* M    = (const float*)d_in[2];   // [128,512]
    const float* Hdec = (const float*)d_in[3];   // [8,1024,256]
    const float* W    = (const float*)d_in[4];   // [32,256]
    const float* w_d  = (const float*)d_in[5];   // [32]

    float* zws = (float*)d_ws;
    unsigned long long* pd64 = (unsigned long long*)(zws + ZWS_FLOATS); // 8B-aligned

    hipMemsetAsync(zws, 0, ZWS_FLOATS * sizeof(float), stream);
    fused_all<<<GRID, 256, 0, stream>>>(H, M, Hdec, W, X, w_d,
                                        zws, pd64, (float*)d_out);
}

// Round 7
// 184.019 us; speedup vs baseline: 1.5975x; 1.5975x over previous
//
#include <hip/hip_runtime.h>
#include <math.h>

// Problem constants (B=8, T=1024, C=32, F=256, D=128, K=512)
#define N_POS 8192
#define D_DIM 128
#define K_DIM 512
#define C_DIM 32
#define F_DIM 256

#define PT 128           // positions per NN tile
#define KW 128           // codewords per NN tile
#define NKT 4            // k-tiles
#define NN_BLOCKS 256    // 64 ptiles x 4 ktiles
#define XG_BLOCKS 256    // 32 bt-rows each (R5-proven shape)
#define GRID (NN_BLOCKS + XG_BLOCKS)
#define NCOPY 8          // striped g_rec/S copies (atomic contention / 8)
#define GCOLS 8448       // 32*256 g_rec + 256 S

// zeroed-ws layout (floats): [0..7] accum (0=sse_rec,1=dsum,2=sse_mem),
// [8..71] ptile counters (64), [72] gcnt, [73..79] pad,
// [80..80+8*8448) g_rec/S copies.  pd64 (u64[4*8192]) follows, un-zeroed.
#define GC_OFF 80
#define ZWS_FLOATS (GC_OFF + NCOPY * GCOLS)    // 67664

// ---------------------------------------------------------------- reductions
__device__ __forceinline__ float block_reduce_256(float v) {
    __shared__ float sbuf[4];
    __syncthreads();
#pragma unroll
    for (int off = 32; off > 0; off >>= 1) v += __shfl_down(v, off);
    const int lane = threadIdx.x & 63;
    const int w    = threadIdx.x >> 6;
    if (lane == 0) sbuf[w] = v;
    __syncthreads();
    return (threadIdx.x == 0) ? (sbuf[0] + sbuf[1] + sbuf[2] + sbuf[3]) : 0.f;
}

__global__ __launch_bounds__(256, 2)
void fused_all(const float* __restrict__ H, const float* __restrict__ M,
               const float* __restrict__ Hdec, const float* __restrict__ W,
               const float* __restrict__ X, const float* __restrict__ w_d,
               float* __restrict__ zws,
               unsigned long long* __restrict__ pd64,
               float* __restrict__ out) {
    // NN: hT 16K + mT 16K + red64 16K = 48K.  XG: Wl 33280 + El 4096 = 37376.
    __shared__ __align__(16) char smem[49152];
    float* accum = zws;
    unsigned int* ptile_cnt = (unsigned int*)(zws + 8);
    unsigned int* gcnt      = (unsigned int*)(zws + 72);
    float* gcopy = zws + GC_OFF;
    const int tid = threadIdx.x;

    if (blockIdx.x < NN_BLOCKS) {
        // ================= NN: 128 pos x 128 k tile, 8x8 acc ==================
        float* hT = (float*)smem;                                   // [32][128]
        float* mT = hT + 4096;                                      // [32][128]
        unsigned long long* red64 = (unsigned long long*)(smem + 32768); // [16][128]

        const int ptile = blockIdx.x >> 2;       // 0..63
        const int ktile = blockIdx.x & 3;        // 0..3
        const int pos0  = ptile * PT;            // 128-aligned, never crosses b
        const int b     = pos0 >> 10;
        const int t0    = pos0 & 1023;
        const int k0    = ktile * KW;
        const float* Hb = H + (b << 17) + t0;

        const int p8 = (tid & 15) << 3;          // pos octet 0..120
        const int q8 = (tid >> 4) << 3;          // k octet 0..120

        float acc[8][8];
#pragma unroll
        for (int i = 0; i < 8; ++i)
#pragma unroll
            for (int j = 0; j < 8; ++j) acc[i][j] = 0.f;

        for (int ch = 0; ch < 4; ++ch) {         // 32-d chunks
            const int d0 = ch << 5;
            __syncthreads();
            {
                int idx = tid * 4;               // 4096 floats each, float4
#pragma unroll
                for (int it = 0; it < 4; ++it, idx += 1024) {
                    const int d = idx >> 7, cc = idx & 127;
                    *(float4*)(hT + idx) =
                        *(const float4*)(Hb + ((size_t)(d0 + d) << 10) + cc);
                    *(float4*)(mT + idx) =
                        *(const float4*)(M + (size_t)(d0 + d) * K_DIM + k0 + cc);
                }
            }
            __syncthreads();
#pragma unroll 2
            for (int d = 0; d < 32; ++d) {
                const float4 h0 = *(const float4*)(hT + (d << 7) + p8);
                const float4 h1 = *(const float4*)(hT + (d << 7) + p8 + 4);
                const float4 m0 = *(const float4*)(mT + (d << 7) + q8);
                const float4 m1 = *(const float4*)(mT + (d << 7) + q8 + 4);
                const float hh[8] = {h0.x, h0.y, h0.z, h0.w, h1.x, h1.y, h1.z, h1.w};
                const float mm[8] = {m0.x, m0.y, m0.z, m0.w, m1.x, m1.y, m1.z, m1.w};
#pragma unroll
                for (int i = 0; i < 8; ++i)
#pragma unroll
                    for (int j = 0; j < 8; ++j)
                        acc[i][j] += fabsf(hh[i] - mm[j]);
            }
        }

        // per-thread argmin over 8 ks (j ascending, strict < -> lowest k on tie);
        // packed u64 (dist_bits, k): u64-min == lexicographic (dist, k)
#pragma unroll
        for (int i = 0; i < 8; ++i) {
            float bd = acc[i][0];
            int   bj = 0;
#pragma unroll
            for (int j = 1; j < 8; ++j)
                if (acc[i][j] < bd) { bd = acc[i][j]; bj = j; }
            red64[(tid >> 4) * PT + p8 + i] =
                ((unsigned long long)__float_as_uint(bd) << 32)
                | (unsigned int)(k0 + q8 + bj);
        }
        __syncthreads();
        if (tid < PT) {
            unsigned long long best = red64[tid];
#pragma unroll
            for (int g = 1; g < 16; ++g) {
                const unsigned long long w = red64[g * PT + tid];
                if (w < best) best = w;
            }
            pd64[ktile * N_POS + pos0 + tid] = best;
        }
        __threadfence();     // release pd64 slice device-wide
        __syncthreads();
        __shared__ int lastp;
        if (tid == 0) lastp = (atomicAdd(&ptile_cnt[ptile], 1u) == 3u);
        __syncthreads();
        if (lastp) {
            __threadfence();                     // acquire other ktiles' pd64
            int* bi_l = (int*)smem;              // hT region is dead
            if (tid < PT) {
                unsigned long long best = ~0ull;
#pragma unroll
                for (int p = 0; p < NKT; ++p) {
                    const unsigned long long w = __hip_atomic_load(
                        pd64 + p * N_POS + pos0 + tid,
                        __ATOMIC_RELAXED, __HIP_MEMORY_SCOPE_AGENT);
                    if (w < best) best = w;
                }
                bi_l[tid] = (int)(unsigned int)(best & 0xffffffffu);
            }
            __syncthreads();
            const int pl = tid & 127;            // position
            const int dh = tid >> 7;             // 0..1, 64 d each
            const int bi = bi_l[pl];
            const float* Hp = H + (b << 17) + t0 + pl;
            float s = 0.f;
#pragma unroll 8
            for (int d = dh * 64; d < dh * 64 + 64; ++d) {
                const float e = Hp[(size_t)d << 10] - M[(size_t)d * K_DIM + bi];
                s += e * e;
            }
            const float r = block_reduce_256(s);
            if (tid == 0) atomicAdd(accum + 2, r);
        }
    } else {
        // ========== XG: xhat + E + loss_rec/disc + grec partials (32 rows) =====
        float* Wl = (float*)smem;                // [32][260]
        float* El = Wl + C_DIM * 260;            // [32][32]
        const int xb  = blockIdx.x - NN_BLOCKS;  // 0..255
        const int bt0 = xb << 5;

#pragma unroll
        for (int it = 0; it < 8; ++it) {         // stage W
            const int i = it * 1024 + tid * 4;
            const float4 v = *(const float4*)(W + i);
            *(float4*)(Wl + (i >> 8) * 260 + (i & 255)) = v;
        }
        __syncthreads();

        const int c  = tid & 31;
        const int rg = tid >> 5;                 // 0..7
        const int r0 = bt0 + rg, r1 = r0 + 8, r2 = r0 + 16, r3 = r0 + 24;

        float a0 = 0.f, a1 = 0.f, a2 = 0.f, a3 = 0.f;
#pragma unroll 4
        for (int f0 = 0; f0 < F_DIM; f0 += 4) {
            const float4 w4 = *(const float4*)(Wl + c * 260 + f0);
            const float4 h0 = *(const float4*)(Hdec + (size_t)r0 * F_DIM + f0);
            const float4 h1 = *(const float4*)(Hdec + (size_t)r1 * F_DIM + f0);
            const float4 h2 = *(const float4*)(Hdec + (size_t)r2 * F_DIM + f0);
            const float4 h3 = *(const float4*)(Hdec + (size_t)r3 * F_DIM + f0);
            a0 += h0.x * w4.x + h0.y * w4.y + h0.z * w4.z + h0.w * w4.w;
            a1 += h1.x * w4.x + h1.y * w4.y + h1.z * w4.z + h1.w * w4.w;
            a2 += h2.x * w4.x + h2.y * w4.y + h2.z * w4.z + h2.w * w4.w;
            a3 += h3.x * w4.x + h3.y * w4.y + h3.z * w4.z + h3.w * w4.w;
        }

        const float wd = w_d[c];
        const float e0 = a0 - X[(size_t)r0 * C_DIM + c];
        const float e1 = a1 - X[(size_t)r1 * C_DIM + c];
        const float e2 = a2 - X[(size_t)r2 * C_DIM + c];
        const float e3 = a3 - X[(size_t)r3 * C_DIM + c];
        El[(rg)      * C_DIM + c] = e0;
        El[(rg + 8)  * C_DIM + c] = e1;
        El[(rg + 16) * C_DIM + c] = e2;
        El[(rg + 24) * C_DIM + c] = e3;
        const float sse = e0 * e0 + e1 * e1 + e2 * e2 + e3 * e3;
        const float dp  = (a0 + a1 + a2 + a3) * wd;
        const float rA = block_reduce_256(sse);
        if (tid == 0) atomicAdd(accum + 0, rA);
        const float rB = block_reduce_256(dp);
        if (tid == 0) atomicAdd(accum + 1, rB);
        __syncthreads();                         // El fully visible

        // grec: thread = f; E rows broadcast from LDS
        float gacc[C_DIM];
#pragma unroll
        for (int cc = 0; cc < C_DIM; ++cc) gacc[cc] = 0.f;
        float sf = 0.f;
#pragma unroll 1
        for (int i = 0; i < 32; ++i) {
            const float hd = Hdec[(size_t)(bt0 + i) * F_DIM + tid];   // coalesced
            sf += hd;
#pragma unroll
            for (int c4 = 0; c4 < 8; ++c4) {
                const float4 e4 = *(const float4*)(El + i * C_DIM + c4 * 4);
                gacc[c4 * 4 + 0] += e4.x * hd;
                gacc[c4 * 4 + 1] += e4.y * hd;
                gacc[c4 * 4 + 2] += e4.z * hd;
                gacc[c4 * 4 + 3] += e4.w * hd;
            }
        }
        float* gc = gcopy + (size_t)(xb & (NCOPY - 1)) * GCOLS;
#pragma unroll 1
        for (int cc = 0; cc < C_DIM; ++cc)
            atomicAdd(&gc[cc * F_DIM + tid], gacc[cc]);
        atomicAdd(&gc[8192 + tid], sf);
    }

    // ============== common epilogue: last block assembles the scalar ==========
    __shared__ int lastg;
    __threadfence();
    __syncthreads();
    if (tid == 0) lastg = (atomicAdd(gcnt, 1u) == (unsigned)(GRID - 1));
    __syncthreads();
    if (lastg) {
        __threadfence();                          // acquire all copies/accum
        float g2 = 0.f;
        for (int i = tid; i < 8192; i += 256) {
            float v = 0.f;
#pragma unroll
            for (int cp = 0; cp < NCOPY; ++cp)
                v += __hip_atomic_load(gcopy + cp * GCOLS + i,
                                       __ATOMIC_RELAXED, __HIP_MEMORY_SCOPE_AGENT);
            g2 += v * v;
        }
        const float rg2 = block_reduce_256(g2);
        float vS = 0.f;
#pragma unroll
        for (int cp = 0; cp < NCOPY; ++cp)
            vS += __hip_atomic_load(gcopy + cp * GCOLS + 8192 + tid,
                                    __ATOMIC_RELAXED, __HIP_MEMORY_SCOPE_AGENT);
        const float rs2 = block_reduce_256(vS * vS);
        float wd2 = (tid < C_DIM) ? w_d[tid] * w_d[tid] : 0.f;
        if (tid < 64) {
#pragma unroll
            for (int off = 32; off > 0; off >>= 1) wd2 += __shfl_down(wd2, off);
        }
        if (tid == 0) {
            const float sse_rec = atomicAdd(accum + 0, 0.f);
            const float dsum    = atomicAdd(accum + 1, 0.f);
            const float sse_mem = atomicAdd(accum + 2, 0.f);
            const float loss_rec = sse_rec / 262144.f;         // /(B*T*C)
            const float loss_d   = -dsum / 8192.f;             // -mean over B*T
            const float loss_m   = 2.f * sse_mem / 1048576.f;  // 2*SSE/(B*D*T)
            const float ngrec    = (2.f / 262144.f) * sqrtf(rg2);
            const float ngd      = sqrtf(wd2 * rs2) / 8192.f;
            const float lmbda    = ngrec / (ngd + 1e-6f);
            out[0] = loss_rec + loss_m + lmbda * loss_d;       // ALPHA = 1
        }
    }
}

// ---------------------------------------------------------------- launcher
extern "C" void kernel_launch(void* const* d_in, const int* in_sizes, int n_in,
                              void* d_out, int out_size, void* d_ws, size_t ws_size,
                              hipStream_t stream) {
    const float* X    = (const float*)d_in[0];   // [8,1024,32]
    const float* H    = (const float*)d_in[1];   // [8,128,1024]
    const float* M    = (const float*)d_in[2];   // [128,512]
    const float* Hdec = (const float*)d_in[3];   // [8,1024,256]
    const float* W    = (const float*)d_in[4];   // [32,256]
    const float* w_d  = (const float*)d_in[5];   // [32]

    float* zws = (float*)d_ws;
    unsigned long long* pd64 = (unsigned long long*)(zws + ZWS_FLOATS); // 8B-aligned

    hipMemsetAsync(zws, 0, ZWS_FLOATS * sizeof(float), stream);
    fused_all<<<GRID, 256, 0, stream>>>(H, M, Hdec, W, X, w_d,
                                        zws, pd64, (float*)d_out);
}